// Round 6
// baseline (1767.124 us; speedup 1.0000x reference)
//
#include <hip/hip_runtime.h>

// LSTM w/ hard-sigmoid gates. T=512, B=64, I=H=512.
// R6 = R4 (last fully-passing structure, global sc0sc1 coherence) + two fixes:
//  (1) LDS partials padded to 65 f32x4 per tile: R4's reduce read was 8-way
//      bank-conflicted (75.5M cyc, tile stride 1024B = 0 mod 128B). Write is
//      a bijection onto 0..63 (uniform); read is uniform-4 (minimal for b128).
//  (2) per-WAVE publish flags: each wave drains its own h stores (vmcnt(0))
//      and flags, removing the full-WG barrier from the publish->flag edge.
//      Flag values stay monotonic (1, then t+2) at fixed memset-zeroed words.
// R5 lesson: XCD-local sc0 sync failed correctness -- reverted entirely.
//
// Workspace: [0,4096)    : flags, 4 reps x 128 u32 (memset to 0)
//            [4096,+128K): h double buffer [2][64][512] bf16

#define T_LEN 512
#define BATCH 64
#define ISZ   512
#define HSZ   512

#define NREP 4
#define WPR  16
#define BR   16
#define JW   32
#define NWG  (NREP * WPR)
#define NTHR 512

typedef __bf16 bf16x8 __attribute__((ext_vector_type(8)));
typedef float  f32x4  __attribute__((ext_vector_type(4)));
typedef float  f32x8  __attribute__((ext_vector_type(8)));
typedef int    i32x4  __attribute__((ext_vector_type(4)));

__device__ __forceinline__ bf16x8 cvt8(f32x4 a, f32x4 b) {
  f32x8 t;
  t[0]=a[0]; t[1]=a[1]; t[2]=a[2]; t[3]=a[3];
  t[4]=b[0]; t[5]=b[1]; t[6]=b[2]; t[7]=b[3];
  return __builtin_convertvector(t, bf16x8);   // v_cvt_pk_bf16_f32 pairs
}

__device__ __forceinline__ float fast_tanh(float v) {
  float e = __expf(2.0f * v);
  return 1.0f - 2.0f / (e + 1.0f);   // exact limits at +-inf
}

__device__ __forceinline__ float hsig(float v) {
  return fminf(fmaxf(0.2f * v + 0.5f, 0.0f), 1.0f);
}

__device__ __forceinline__ unsigned pack_bf16(float a, float b) {
  union { __bf16 h[2]; unsigned u; } p;
  p.h[0] = (__bf16)a; p.h[1] = (__bf16)b;
  return p.u;
}

// h loads: sc0 sc1 = bypass L1/L2, served at the device-coherent point
#define HLOAD(i, o)                                                        \
  asm volatile("global_load_dwordx4 %0, %1, off offset:" #o " sc0 sc1"     \
               : "=v"(hfrag[i]) : "v"(hr));
// x prefetch: plain cached loads, asm-pinned so they issue at the step tail
#define XLOAD(i, o)                                                        \
  asm volatile("global_load_dwordx4 %0, %1, off offset:" #o                \
               : "=v"(xpre[i]) : "v"(xr));

__global__ __launch_bounds__(NTHR, 2) void lstm_kernel(
    const float* __restrict__ x,      // [T][B][I]
    const float* __restrict__ h0,     // [B][H]
    const float* __restrict__ c0,     // [B][H]
    const float* __restrict__ w_ih,   // [4H][I]
    const float* __restrict__ w_hh,   // [4H][H]
    const float* __restrict__ b_ih,   // [4H]
    const float* __restrict__ b_hh,   // [4H]
    float* __restrict__ out,          // [T][B][H] ++ hn[B][H] ++ cn[B][H]
    unsigned* __restrict__ flags,     // [NREP][16 wg][8 wave] monotonic words
    __bf16* __restrict__ hbuf)        // [2][B][H]
{
  const int bid = blockIdx.x;
  const int rep = bid >> 4;           // 0..3
  const int wgi = bid & 15;           // 0..15
  const int B0  = rep * BR;
  const int J0  = wgi * JW;

  const int tid  = threadIdx.x;
  const int lane = tid & 63;
  const int wv   = tid >> 6;          // 0..7
  const int l15  = lane & 15;
  const int hi   = lane >> 4;         // 0..3
  const int lk   = hi << 3;
  const bool xw  = (wv < 4);          // x-waves 0-3, h-waves 4-7
  const int  K0  = (wv & 3) * 128;    // this wave's K-slice base

  unsigned* myf    = flags + rep * 128;
  unsigned* hbuf32 = (unsigned*)hbuf;

  // ---- weights -> registers: 128 interleaved rows (row = 4*j_local + gate),
  //      K-slice [K0,K0+128) of w_ih (x-waves) or w_hh (h-waves) ----
  bf16x8 wfrag[32];                   // [tile 0..7][ks 0..3]
  {
    const float* W = xw ? w_ih : w_hh;
#pragma unroll
    for (int tile = 0; tile < 8; ++tile) {
      const int r    = tile * 16 + l15;              // WG-local row (A: row=l15)
      const int grow = (r & 3) * HSZ + J0 + (r >> 2);
      const float* wp = W + (size_t)grow * 512 + K0 + lk;
#pragma unroll
      for (int ks = 0; ks < 4; ++ks) {
        f32x4 a = *(const f32x4*)(wp + ks * 32);
        f32x4 b = *(const f32x4*)(wp + ks * 32 + 4);
        wfrag[tile * 4 + ks] = cvt8(a, b);
      }
    }
  }

  // ---- update-phase ids: thread owns (batch ub, column uj) ----
  const int ub     = tid >> 5;        // 0..15
  const int uj     = tid & 31;        // 0..31
  const int tile_u = uj >> 2;
  const int hi_u   = uj & 3;
  const size_t urow = (size_t)(B0 + ub) * HSZ + (size_t)(J0 + uj);

  f32x4 bias4;
#pragma unroll
  for (int q = 0; q < 4; ++q)
    bias4[q] = b_ih[q * HSZ + J0 + uj] + b_hh[q * HSZ + J0 + uj];

  float cst = c0[urow];

  // ---- x[0] register prefetch (x-waves) ----
  f32x4 xpre[8];
  if (xw) {
    const float* xr = x + (size_t)(B0 + l15) * ISZ + K0 + lk;
    XLOAD(0, 0)   XLOAD(1, 16)  XLOAD(2, 128) XLOAD(3, 144)
    XLOAD(4, 256) XLOAD(5, 272) XLOAD(6, 384) XLOAD(7, 400)
  }

  // ---- h0 publish; per-wave drain + flag=1 ----
  {
    float hv0 = h0[urow];
    float hp  = __shfl_xor(hv0, 1);
    if (!(tid & 1))
      __hip_atomic_store(&hbuf32[urow >> 1], pack_bf16(hv0, hp),
                         __ATOMIC_RELAXED, __HIP_MEMORY_SCOPE_AGENT);
  }
  asm volatile("s_waitcnt vmcnt(0)" ::: "memory");
  if (lane == 0)
    __hip_atomic_store(&myf[wgi * 8 + wv], 1u,
                       __ATOMIC_RELAXED, __HIP_MEMORY_SCOPE_AGENT);

  // partials: [wave][tile] blocks of 65 f32x4 (64 data + 1 pad).
  // stride 65*16B == 4 banks (mod 32): write bijective/uniform, read uniform-4
  __shared__ __align__(16) f32x4 lds_p[8 * 8 * 65];

  for (int t = 0; t < T_LEN; ++t) {
    f32x4 acc[8];
#pragma unroll
    for (int i = 0; i < 8; ++i) acc[i] = (f32x4)(0.0f);

    if (xw) {
      // x[t] prefetched last iteration; drain, keep MFMAs below (rule #18)
      asm volatile("s_waitcnt vmcnt(0)" ::: "memory");
      __builtin_amdgcn_sched_barrier(0);
      bf16x8 bx[4];
#pragma unroll
      for (int ks = 0; ks < 4; ++ks) bx[ks] = cvt8(xpre[2 * ks], xpre[2 * ks + 1]);
#pragma unroll
      for (int tile = 0; tile < 8; ++tile)
#pragma unroll
        for (int ks = 0; ks < 4; ++ks)
          acc[tile] = __builtin_amdgcn_mfma_f32_16x16x32_bf16(
              wfrag[tile * 4 + ks], bx[ks], acc[tile], 0, 0, 0);
    } else {
      // h-waves: wait until all 8 waves of all 16 WGs published h_t (>= t+1)
      const unsigned tgt = (unsigned)(t + 1);
      long g = 0;
      for (;;) {
        unsigned va = __hip_atomic_load(&myf[lane], __ATOMIC_RELAXED,
                                        __HIP_MEMORY_SCOPE_AGENT);
        unsigned vb = __hip_atomic_load(&myf[64 + lane], __ATOMIC_RELAXED,
                                        __HIP_MEMORY_SCOPE_AGENT);
        if (__all((int)(va >= tgt && vb >= tgt))) break;
        __builtin_amdgcn_s_sleep(1);
        if (++g > (1L << 20)) break;   // safety net: corrupt, don't hang
      }
      __builtin_amdgcn_sched_barrier(0);

      const __bf16* hr = hbuf + (size_t)(t & 1) * BATCH * HSZ
                              + (size_t)(B0 + l15) * HSZ + K0 + lk;
      i32x4 hfrag[4];
      HLOAD(0, 0) HLOAD(1, 64) HLOAD(2, 128) HLOAD(3, 192)
      asm volatile("s_waitcnt vmcnt(0)" ::: "memory");
      __builtin_amdgcn_sched_barrier(0);   // rule #18: MFMAs stay below wait
#pragma unroll
      for (int tile = 0; tile < 8; ++tile)
#pragma unroll
        for (int ks = 0; ks < 4; ++ks)
          acc[tile] = __builtin_amdgcn_mfma_f32_16x16x32_bf16(
              wfrag[tile * 4 + ks], __builtin_bit_cast(bf16x8, hfrag[ks]),
              acc[tile], 0, 0, 0);
    }

#pragma unroll
    for (int tile = 0; tile < 8; ++tile)
      lds_p[(wv * 8 + tile) * 65 + l15 * 4 + hi] = acc[tile];

    __syncthreads();                   // #1: all partials visible

    // reduce 8 K-slices + bias -> (i,f,g,o) of (ub, uj); lane-local update
    f32x4 gsum = bias4;
#pragma unroll
    for (int w = 0; w < 8; ++w)
      gsum += lds_p[(w * 8 + tile_u) * 65 + ub * 4 + hi_u];

    float iv = hsig(gsum[0]), fv = hsig(gsum[1]), ov = hsig(gsum[3]);
    float gv = fast_tanh(gsum[2]);
    cst = fv * cst + iv * gv;
    float hv = ov * fast_tanh(cst);

    // publish h_{t+1} (packed u32), per-wave drain, per-wave flag
    {
      float hp = __shfl_xor(hv, 1);
      if (!(tid & 1))
        __hip_atomic_store(
            &hbuf32[((size_t)((t + 1) & 1) * BATCH * HSZ + urow) >> 1],
            pack_bf16(hv, hp), __ATOMIC_RELAXED, __HIP_MEMORY_SCOPE_AGENT);
    }
    asm volatile("s_waitcnt vmcnt(0)" ::: "memory");
    if (lane == 0)
      __hip_atomic_store(&myf[wgi * 8 + wv], (unsigned)(t + 2),
                         __ATOMIC_RELAXED, __HIP_MEMORY_SCOPE_AGENT);

    // off-critical-path: out stores (drained by a later barrier/drain)
    out[(size_t)t * BATCH * HSZ + urow] = hv;
    if (t == T_LEN - 1) {
      out[(size_t)T_LEN * BATCH * HSZ + urow] = hv;                        // hn
      out[(size_t)T_LEN * BATCH * HSZ + (size_t)BATCH * HSZ + urow] = cst; // cn
    }

    __syncthreads();                   // #2: protect lds_p reuse next iter

    // x[t+1] register prefetch -- a full step of latency cover
    if (xw && (t + 1) < T_LEN) {
      const float* xr = x + ((size_t)(t + 1) * BATCH + B0 + l15) * ISZ + K0 + lk;
      XLOAD(0, 0)   XLOAD(1, 16)  XLOAD(2, 128) XLOAD(3, 144)
      XLOAD(4, 256) XLOAD(5, 272) XLOAD(6, 384) XLOAD(7, 400)
    }
  }
}

extern "C" void kernel_launch(void* const* d_in, const int* in_sizes, int n_in,
                              void* d_out, int out_size, void* d_ws, size_t ws_size,
                              hipStream_t stream) {
  const float* x    = (const float*)d_in[0];
  const float* h0   = (const float*)d_in[1];
  const float* c0   = (const float*)d_in[2];
  const float* w_ih = (const float*)d_in[3];
  const float* w_hh = (const float*)d_in[4];
  const float* b_ih = (const float*)d_in[5];
  const float* b_hh = (const float*)d_in[6];
  float* out = (float*)d_out;

  unsigned* flags = (unsigned*)d_ws;
  __bf16* hbuf    = (__bf16*)((char*)d_ws + 4096);
  // needs 4096 + 2*64*512*2 = ~132KB of workspace

  hipMemsetAsync(d_ws, 0, 4096, stream);  // zero flag words (ws is poisoned)

  hipLaunchKernelGGL(lstm_kernel, dim3(NWG), dim3(NTHR), 0, stream,
                     x, h0, c0, w_ih, w_hh, b_ih, b_hh, out, flags, hbuf);
}